// Round 5
// baseline (616.120 us; speedup 1.0000x reference)
//
#include <hip/hip_runtime.h>
#include <math.h>

// Problem dims (fixed by setup_inputs)
#define NR   1500     // rows of X_m  (Nt - Lt)
#define NTT  1508     // Nt
#define QD   12       // D
#define LT   8
#define DIN  192      // 2*Lt*Q
#define MM   192      // M
#define JITTER 1e-6f
#define PRUNE_CUT -80.0f   // exp(-80)=1.8e-35; skipped mass << absmax threshold

// ---- workspace layout (float offsets) ----
#define OFF_W2    0
#define OFF_WU2   288000
#define OFF_P1    576000
#define OFF_F     576000      // alias: F overwrites P1 after k_psi1
#define OFF_R1    864000
#define OFF_S1    1152000
#define OFF_NLIST 1152000     // alias: survivor list overwrites S1 after k_psi1
#define OFF_S2    1153500
#define OFF_ZST   1155000
#define OFF_V     1155000     // alias: V overwrites ZST after k_kuu
#define OFF_D2ZZ  1191864
#define OFF_KUU   1228728
#define OFF_PSI1  1265592
#define OFF_PSI2  1553592
#define OFF_LC    1590456
#define OFF_LC2   1627320
#define OFF_G     1664184
#define OFF_SCAL  1666488
#define OFF_RUB   1666504     // 1500 ordered-uint row upper bounds
// scal slots: 0 trace_raw, 2 ||Y||^2, 3 sum(X_vo), 4 sum(X_mo^2),
//             5 sum(log X_vo), 6 sum(X_mb^2+X_vb), 7 0.5*logdetKuu, 8 0.5*logdetC2,
//             12 survivor count (int)

__device__ __forceinline__ float wave_reduce(float s) {
    s += __shfl_down(s, 32); s += __shfl_down(s, 16); s += __shfl_down(s, 8);
    s += __shfl_down(s, 4);  s += __shfl_down(s, 2);  s += __shfl_down(s, 1);
    return s;
}
__device__ __forceinline__ float bfly_sum(float s) {
    s += __shfl_xor(s, 32); s += __shfl_xor(s, 16); s += __shfl_xor(s, 8);
    s += __shfl_xor(s, 4);  s += __shfl_xor(s, 2);  s += __shfl_xor(s, 1);
    return s;
}

// ---------------- per-n prep: hankel rows, d1/d2 derived arrays, s1/s2 -------
__global__ __launch_bounds__(192) void k_prep(
    const float* __restrict__ Xm_m, const float* __restrict__ Xm_v,
    const float* __restrict__ X_mean, const float* __restrict__ X_var,
    const float* __restrict__ kern_ls, float* __restrict__ ws)
{
    int n = blockIdx.x;
    int q = threadIdx.x;  // 0..191
    float u, v;
    if (q < 96) {
        int l = q / QD, qq = q - l * QD;
        int r = n + l;                       // X_mean[:Nt-1] hankel
        u = X_mean[r * QD + qq]; v = X_var[r * QD + qq];
    } else {
        int j = q - 96; int l = j / QD, qq = j - l * QD;
        int r = 1 + n + l;                   // Xm_m[1:Nt] hankel
        u = Xm_m[r * QD + qq]; v = Xm_v[r * QD + qq];
    }
    float ls = kern_ls[q]; float l2 = ls * ls;
    float d1 = l2 + v, d2 = l2 + 2.0f * v;
    float i1 = 1.0f / d1, i2 = 1.0f / d2;
    ws[OFF_P1  + n * DIN + q] = u * i1;
    ws[OFF_R1  + n * DIN + q] = i1;
    ws[OFF_W2  + n * DIN + q] = i2;
    ws[OFF_WU2 + n * DIN + q] = u * i2;

    float v0 = log1pf(v / l2);          // -> logdet1 part
    float v1 = log1pf(2.0f * v / l2);   // -> logdet2 part
    float v2 = u * u * i1;              // -> -0.5*sum u^2/d1
    float v3 = u * u * i2;              // -> a[n]
    v0 = bfly_sum(v0); v1 = bfly_sum(v1); v2 = bfly_sum(v2); v3 = bfly_sum(v3);
    __shared__ float part[3][4];
    if ((q & 63) == 0) {
        int w = q >> 6;
        part[w][0] = v0; part[w][1] = v1; part[w][2] = v2; part[w][3] = v3;
    }
    __syncthreads();
    if (q == 0) {
        float S0 = part[0][0] + part[1][0] + part[2][0];
        float S1 = part[0][1] + part[1][1] + part[2][1];
        float S2 = part[0][2] + part[1][2] + part[2][2];
        float S3 = part[0][3] + part[1][3] + part[2][3];
        ws[OFF_S1 + n] = -0.5f * (S0 + S2);
        ws[OFF_S2 + n] = -0.5f * S1 - S3;
    }
}

// ---------------- Zs transposed (for coalesced d2zz) ------------------------
__global__ void k_zst(const float* __restrict__ Z, const float* __restrict__ kern_ls,
                      float* __restrict__ ws)
{
    int idx = blockIdx.x * 256 + threadIdx.x;
    if (idx >= MM * DIN) return;
    int q = idx / MM, p = idx - q * MM;
    ws[OFF_ZST + idx] = Z[p * DIN + q] / kern_ls[q];
}

// ---------------- d2zz + Kuu ------------------------------------------------
__global__ void k_kuu(const float* __restrict__ kern_var, float* __restrict__ ws)
{
    int idx = blockIdx.x * 256 + threadIdx.x;
    if (idx >= MM * MM) return;
    int m = idx / MM, p = idx - m * MM;
    const float* zst = ws + OFF_ZST;
    float d = 0.0f;
    for (int q = 0; q < DIN; q++) {
        float a = zst[q * MM + m], b = zst[q * MM + p];
        float t = a - b; d = fmaf(t, t, d);
    }
    ws[OFF_D2ZZ + idx] = d;
    float kv = *kern_var;
    ws[OFF_KUU + idx] = kv * __expf(-0.5f * d) + ((m == p) ? JITTER : 0.0f);
}

// ---------------- psi1 (1500 x 192), tiled ---------------------------------
__global__ __launch_bounds__(256) void k_psi1(
    const float* __restrict__ Z, const float* __restrict__ kern_var,
    float* __restrict__ ws)
{
    int tx = threadIdx.x & 15, ty = threadIdx.x >> 4;
    int n = blockIdx.x * 16 + ty;
    int m = blockIdx.y * 16 + tx;
    __shared__ float Ps[16][17], Rs[16][17], Zs[16][17], Z2s[16][17];
    float dot1 = 0.0f, dot2 = 0.0f;
    for (int qc = 0; qc < 12; qc++) {
        int q0 = qc * 16;
        Ps[ty][tx] = (n < NR) ? ws[OFF_P1 + n * DIN + q0 + tx] : 0.0f;
        Rs[ty][tx] = (n < NR) ? ws[OFF_R1 + n * DIN + q0 + tx] : 0.0f;
        float z = Z[(blockIdx.y * 16 + ty) * DIN + q0 + tx];
        Zs[ty][tx] = z; Z2s[ty][tx] = z * z;
        __syncthreads();
        #pragma unroll
        for (int k = 0; k < 16; k++) {
            dot1 = fmaf(Ps[ty][k], Zs[tx][k], dot1);
            dot2 = fmaf(Rs[ty][k], Z2s[tx][k], dot2);
        }
        __syncthreads();
    }
    if (n < NR) {
        float kv = *kern_var;
        ws[OFF_PSI1 + n * MM + m] = kv * __expf(ws[OFF_S1 + n] + dot1 - 0.5f * dot2);
    }
}

// ---- F[n,m] = b - 0.25c; per-n max_m(b) via ordered-uint atomicMax ---------
__device__ __forceinline__ unsigned ord_encode(float f) {
    unsigned u = __float_as_uint(f);
    return (u & 0x80000000u) ? ~u : (u | 0x80000000u);
}
__global__ __launch_bounds__(256) void k_bc(
    const float* __restrict__ Z, float* __restrict__ ws)
{
    int tx = threadIdx.x & 15, ty = threadIdx.x >> 4;
    int n = blockIdx.x * 16 + ty;
    int m = blockIdx.y * 16 + tx;
    __shared__ float Us[16][17], Ws[16][17], Zs[16][17];
    float dotB = 0.0f, dotC = 0.0f;
    for (int qc = 0; qc < 12; qc++) {
        int q0 = qc * 16;
        Us[ty][tx] = (n < NR) ? ws[OFF_WU2 + n * DIN + q0 + tx] : 0.0f;
        Ws[ty][tx] = (n < NR) ? ws[OFF_W2  + n * DIN + q0 + tx] : 0.0f;
        Zs[ty][tx] = Z[(blockIdx.y * 16 + ty) * DIN + q0 + tx];
        __syncthreads();
        #pragma unroll
        for (int k = 0; k < 16; k++) {
            float z = Zs[tx][k];
            dotB = fmaf(z, Us[ty][k], dotB);
            dotC = fmaf(z * z, Ws[ty][k], dotC);
        }
        __syncthreads();
    }
    if (n < NR) ws[OFF_F + n * MM + m] = fmaf(-0.25f, dotC, dotB);
    // per-n max of dotB over this block's 16 m (width-16 shuffle groups = tx)
    float mx = dotB;
    mx = fmaxf(mx, __shfl_down(mx, 8, 16));
    mx = fmaxf(mx, __shfl_down(mx, 4, 16));
    mx = fmaxf(mx, __shfl_down(mx, 2, 16));
    mx = fmaxf(mx, __shfl_down(mx, 1, 16));
    if (tx == 0 && n < NR)
        atomicMax((unsigned*)(ws + OFF_RUB) + n, ord_encode(mx));
}

// ---- survivor compaction from row upper bounds -----------------------------
// expo[n,m,p] <= s2[n] + b[n,m] + b[n,p] <= s2[n] + 2*max_m b[n,m]
__global__ void k_rowmax(float* __restrict__ ws)
{
    int n = blockIdx.x * 256 + threadIdx.x;
    if (n >= NR) return;
    unsigned key = ((const unsigned*)(ws + OFF_RUB))[n];
    float f = (key & 0x80000000u) ? __uint_as_float(key ^ 0x80000000u)
                                  : __uint_as_float(~key);
    float bound = ws[OFF_S2 + n] + 2.0f * f;
    if (key != 0u && bound > PRUNE_CUT) {
        int idx = atomicAdd((int*)(ws + OFF_SCAL + 12), 1);
        ((int*)(ws + OFF_NLIST))[idx] = n;
    }
}

// ---------------- psi2: sum over surviving n, finalize fused ----------------
#define ZR 196   // LDS row stride
__global__ __launch_bounds__(256) void k_psi2(
    const float* __restrict__ Z, const float* __restrict__ kern_var,
    float* __restrict__ ws)
{
    int count = *((const int*)(ws + OFF_SCAL + 12));   // grid-uniform
    int tx = threadIdx.x & 15, ty = threadIdx.x >> 4;
    int m0 = blockIdx.x * 32, p0 = blockIdx.y * 32;
    int mA = m0 + 2 * ty, pA = p0 + 2 * tx;
    float a00 = 0, a01 = 0, a10 = 0, a11 = 0;
    if (count > 0) {
        __shared__ __align__(16) float Zm[32 * ZR], Zp[32 * ZR];
        for (int idx = threadIdx.x; idx < 32 * DIN; idx += 256) {
            int r = idx / DIN, q = idx - r * DIN;
            Zm[r * ZR + q] = Z[(m0 + r) * DIN + q];
            Zp[r * ZR + q] = Z[(p0 + r) * DIN + q];
        }
        __syncthreads();
        const float* w2base = ws + OFF_W2;
        const float* F      = ws + OFF_F;
        const float* s2arr  = ws + OFF_S2;
        const int* list     = (const int*)(ws + OFF_NLIST);
        const float4* zm0 = (const float4*)(Zm + (2 * ty    ) * ZR);
        const float4* zm1 = (const float4*)(Zm + (2 * ty + 1) * ZR);
        const float4* zp0 = (const float4*)(Zp + (2 * tx    ) * ZR);
        const float4* zp1 = (const float4*)(Zp + (2 * tx + 1) * ZR);
        for (int li = 0; li < count; li++) {
            int n = list[li];
            const float4* w2p = (const float4*)(w2base + n * DIN);
            float e00 = 0, e01 = 0, e10 = 0, e11 = 0;
            #pragma unroll 4
            for (int g = 0; g < DIN / 4; g++) {
                float4 w  = w2p[g];
                float4 a  = zm0[g], b = zm1[g], c = zp0[g], d = zp1[g];
                float wp0, wp1;
                wp0 = w.x * c.x; wp1 = w.x * d.x;
                e00 = fmaf(a.x, wp0, e00); e01 = fmaf(a.x, wp1, e01);
                e10 = fmaf(b.x, wp0, e10); e11 = fmaf(b.x, wp1, e11);
                wp0 = w.y * c.y; wp1 = w.y * d.y;
                e00 = fmaf(a.y, wp0, e00); e01 = fmaf(a.y, wp1, e01);
                e10 = fmaf(b.y, wp0, e10); e11 = fmaf(b.y, wp1, e11);
                wp0 = w.z * c.z; wp1 = w.z * d.z;
                e00 = fmaf(a.z, wp0, e00); e01 = fmaf(a.z, wp1, e01);
                e10 = fmaf(b.z, wp0, e10); e11 = fmaf(b.z, wp1, e11);
                wp0 = w.w * c.w; wp1 = w.w * d.w;
                e00 = fmaf(a.w, wp0, e00); e01 = fmaf(a.w, wp1, e01);
                e10 = fmaf(b.w, wp0, e10); e11 = fmaf(b.w, wp1, e11);
            }
            float s2n = s2arr[n];
            float Fm0 = F[n * MM + mA], Fm1 = F[n * MM + mA + 1];
            float Fp0 = F[n * MM + pA], Fp1 = F[n * MM + pA + 1];
            a00 += __expf(s2n + Fm0 + Fp0 - 0.5f * e00);
            a01 += __expf(s2n + Fm0 + Fp1 - 0.5f * e01);
            a10 += __expf(s2n + Fm1 + Fp0 - 0.5f * e10);
            a11 += __expf(s2n + Fm1 + Fp1 - 0.5f * e11);
        }
    }
    // fused finalize: psi2 = kv^2 * exp(-0.25*d2zz) * sum
    float kv = *kern_var; float kv2 = kv * kv;
    const float* dz = ws + OFF_D2ZZ;
    float* P2 = ws + OFF_PSI2;
    P2[(mA    ) * MM + pA    ] = kv2 * __expf(-0.25f * dz[(mA    ) * MM + pA    ]) * a00;
    P2[(mA    ) * MM + pA + 1] = kv2 * __expf(-0.25f * dz[(mA    ) * MM + pA + 1]) * a01;
    P2[(mA + 1) * MM + pA    ] = kv2 * __expf(-0.25f * dz[(mA + 1) * MM + pA    ]) * a10;
    P2[(mA + 1) * MM + pA + 1] = kv2 * __expf(-0.25f * dz[(mA + 1) * MM + pA + 1]) * a11;
}

// ---------------- dual blocked LDL^T (block 0: Kuu, block 1: C2) ------------
// Panel (192x32) by wave 0 in registers: LDL rank-1 uses RAW column values,
// so the broadcast never waits on sqrt/div. Mirror folds sqrt(d) so the
// trailing update stays pure fma. Trailing: 8x8 register tiles (4 b128 -> 64 fma).
// Output: unit-lower L with d on the diagonal; logdet = sum log d.
#define ALD 196
#define NB  32
__global__ __launch_bounds__(256) void k_chol2(float* __restrict__ ws,
                                               const float* __restrict__ lik)
{
    __shared__ __align__(16) float A[MM * ALD];
    int tid = threadIdx.x;
    bool isC2 = (blockIdx.x == 1);
    const float* Kuu  = ws + OFF_KUU;
    const float* psi2 = ws + OFF_PSI2;
    float inv_s2 = 1.0f / (*lik);
    for (int idx = tid; idx < MM * MM; idx += 256) {
        int i = idx / MM, j = idx - i * MM;
        float v = Kuu[idx];
        if (isC2) v = fmaf(psi2[idx], inv_s2, v);
        A[i * ALD + j] = v;
    }
    __syncthreads();

    float logacc = 0.0f;
    int ty = tid >> 4, tx = tid & 15;
    for (int p = 0; p < MM / NB; p++) {
        int k0 = p * NB;
        int e  = k0 + NB;
        if (tid < 64) {
            int lane = tid;
            float P[3][NB];
            #pragma unroll
            for (int s = 0; s < 3; s++) {
                int r = lane + 64 * s;
                #pragma unroll
                for (int g = 0; g < NB / 4; g++) {
                    float4 v = *(const float4*)&A[r * ALD + k0 + 4 * g];
                    P[s][4*g] = v.x; P[s][4*g+1] = v.y; P[s][4*g+2] = v.z; P[s][4*g+3] = v.w;
                }
            }
            int sD = k0 >> 6;         // register slice holding the diag block
            int lD = k0 & 63;         // first lane of the diag block
            #pragma unroll
            for (int c = 0; c < NB; c++) {
                int k = k0 + c;
                float colc = (sD == 0) ? P[0][c] : ((sD == 1) ? P[1][c] : P[2][c]); // RAW
                float dkk = __shfl(colc, lD + c);
                float inv = 1.0f / dkk;
                logacc += logf(dkk);
                float m0 = (lane       > k) ? P[0][c] * inv : 0.0f;
                float m1 = (lane + 64  > k) ? P[1][c] * inv : 0.0f;
                float m2 = (lane + 128 > k) ? P[2][c] * inv : 0.0f;
                P[0][c] = (lane       > k) ? m0 : P[0][c];   // store unit-L; diag keeps d
                P[1][c] = (lane + 64  > k) ? m1 : P[1][c];
                P[2][c] = (lane + 128 > k) ? m2 : P[2][c];
                #pragma unroll
                for (int j = c + 1; j < NB; j++) {
                    float w = __shfl(colc, lD + j);          // RAW A[k0+j][c]
                    P[0][j] = fmaf(-m0, w, P[0][j]);
                    P[1][j] = fmaf(-m1, w, P[1][j]);
                    P[2][j] = fmaf(-m2, w, P[2][j]);
                }
            }
            #pragma unroll
            for (int s = 0; s < 3; s++) {
                int r = lane + 64 * s;
                #pragma unroll
                for (int g = 0; g < NB / 4; g++) {
                    float4 v = make_float4(P[s][4*g], P[s][4*g+1], P[s][4*g+2], P[s][4*g+3]);
                    *(float4*)&A[r * ALD + k0 + 4 * g] = v;
                }
            }
        }
        __syncthreads();
        int T = MM - e;
        if (T > 0) {
            // mirror: A[k0+c][j>=e] = L[j][k0+c] * sqrt(d_c)  (trailing stays pure fma)
            for (int idx = tid; idx < NB * T; idx += 256) {
                int c = idx / T, j = e + (idx - c * T);
                float d = A[(k0 + c) * ALD + (k0 + c)];
                A[(k0 + c) * ALD + j] = A[j * ALD + k0 + c] * sqrtf(d);
            }
            __syncthreads();
            // trailing update: [e,192)^2 -= M^T M with M = mirrored rows
            int nT = (T + 127) / 128;
            for (int bi = 0; bi < nT; bi++)
            for (int bj = 0; bj < nT; bj++) {
                int i0 = e + 128 * bi + 8 * ty;
                int j0 = e + 128 * bj + 8 * tx;
                int ic = (i0 < MM - 8) ? i0 : (MM - 8);
                int jc = (j0 < MM - 8) ? j0 : (MM - 8);
                float4 acc[8][2];
                #pragma unroll
                for (int r = 0; r < 8; r++) {
                    acc[r][0] = *(const float4*)&A[(ic + r) * ALD + jc];
                    acc[r][1] = *(const float4*)&A[(ic + r) * ALD + jc + 4];
                }
                #pragma unroll 4
                for (int c = 0; c < NB; c++) {
                    const float* row = &A[(k0 + c) * ALD];
                    float4 av0 = *(const float4*)&row[ic];
                    float4 av1 = *(const float4*)&row[ic + 4];
                    float4 bv0 = *(const float4*)&row[jc];
                    float4 bv1 = *(const float4*)&row[jc + 4];
                    float avs[8] = {av0.x, av0.y, av0.z, av0.w, av1.x, av1.y, av1.z, av1.w};
                    #pragma unroll
                    for (int r = 0; r < 8; r++) {
                        float a = avs[r];
                        acc[r][0].x = fmaf(-a, bv0.x, acc[r][0].x);
                        acc[r][0].y = fmaf(-a, bv0.y, acc[r][0].y);
                        acc[r][0].z = fmaf(-a, bv0.z, acc[r][0].z);
                        acc[r][0].w = fmaf(-a, bv0.w, acc[r][0].w);
                        acc[r][1].x = fmaf(-a, bv1.x, acc[r][1].x);
                        acc[r][1].y = fmaf(-a, bv1.y, acc[r][1].y);
                        acc[r][1].z = fmaf(-a, bv1.z, acc[r][1].z);
                        acc[r][1].w = fmaf(-a, bv1.w, acc[r][1].w);
                    }
                }
                if (ic == i0 && jc == j0) {
                    #pragma unroll
                    for (int r = 0; r < 8; r++) {
                        *(float4*)&A[(i0 + r) * ALD + j0]     = acc[r][0];
                        *(float4*)&A[(i0 + r) * ALD + j0 + 4] = acc[r][1];
                    }
                }
            }
            __syncthreads();
        }
    }
    float* dst = ws + (isC2 ? OFF_LC2 : OFF_LC);
    for (int idx = tid; idx < MM * MM; idx += 256) {
        int i = idx / MM, j = idx - i * MM;
        dst[idx] = A[i * ALD + j];
    }
    if (tid == 0) ws[OFF_SCAL + (isC2 ? 8 : 7)] = 0.5f * logacc;
}

// ---------------- V = L^{-1} (unit-lower): one wave per column --------------
__global__ __launch_bounds__(64) void k_trinv(float* __restrict__ ws)
{
    const float* L = ws + OFF_LC;
    float* V = ws + OFF_V;
    int j = blockIdx.x, l = threadIdx.x;
    int k0 = j + l, k1 = k0 + 64, k2 = k0 + 128;
    float x0 = 0, x1 = 0, x2 = 0;
    for (int i = j; i < MM; i++) {
        const float* Lr = L + i * MM;
        float s = 0.0f;
        if (k0 < i) s = fmaf(Lr[k0], x0, s);
        if (k1 < i) s = fmaf(Lr[k1], x1, s);
        if (k2 < i) s = fmaf(Lr[k2], x2, s);
        #pragma unroll
        for (int off = 1; off < 64; off <<= 1) s += __shfl_xor(s, off);
        float xi = ((i == j) ? 1.0f : 0.0f) - s;   // unit diagonal: no divide
        if (k0 == i) x0 = xi;
        if (k1 == i) x1 = xi;
        if (k2 == i) x2 = xi;
        if (l == 0) V[i * MM + j] = xi;
    }
}

// -------- trace_raw = sum_i (V[i,:] psi2 V[i,:]^T) / d_i --------------------
__global__ __launch_bounds__(256) void k_tracedot(float* __restrict__ ws)
{
    int i = blockIdx.x, tid = threadIdx.x;
    __shared__ float vrow[MM];
    const float* V = ws + OFF_V;
    const float* P = ws + OFF_PSI2;
    for (int a = tid; a < MM; a += 256) vrow[a] = (a <= i) ? V[i * MM + a] : 0.0f;
    __syncthreads();
    float acc = 0.0f;
    for (int a = tid; a <= i; a += 256) {
        const float* Pr = P + a * MM;
        float inner = 0.0f;
        for (int b = 0; b <= i; b++) inner = fmaf(Pr[b], vrow[b], inner);
        acc = fmaf(vrow[a], inner, acc);
    }
    __shared__ float red[256];
    red[tid] = acc; __syncthreads();
    if (tid < 128) red[tid] += red[tid + 128];
    __syncthreads();
    if (tid < 64) {
        float s = red[tid] + red[tid + 64];
        s = wave_reduce(s);
        if (tid == 0) {
            float di = ws[OFF_LC + i * MM + i];   // LDL diagonal
            atomicAdd(&ws[OFF_SCAL + 0], s / di);
        }
    }
}

// ---------------- G = psi1^T @ X_mo  (192 x 12): one block per m ------------
__global__ __launch_bounds__(256) void k_g(const float* __restrict__ X_mean,
                                           float* __restrict__ ws)
{
    int m = blockIdx.x, tid = threadIdx.x;
    const float* psi1 = ws + OFF_PSI1;
    float g[QD];
    #pragma unroll
    for (int d = 0; d < QD; d++) g[d] = 0.0f;
    for (int n = tid; n < NR; n += 256) {
        float p = psi1[n * MM + m];
        const float* xr = X_mean + (LT + n) * QD;
        #pragma unroll
        for (int d = 0; d < QD; d++) g[d] = fmaf(p, xr[d], g[d]);
    }
    __shared__ float red[256];
    for (int d = 0; d < QD; d++) {
        red[tid] = g[d]; __syncthreads();
        if (tid < 128) red[tid] += red[tid + 128];
        __syncthreads();
        if (tid < 64) {
            float s = red[tid] + red[tid + 64];
            s = wave_reduce(s);
            if (tid == 0) ws[OFF_G + m * QD + d] = s;
        }
        __syncthreads();
    }
}

// ------ Y = L2^{-1} G (unit-lower, 12 RHS); accumulate sum Y_i^2 / d_i ------
__global__ __launch_bounds__(64) void k_solve12(float* __restrict__ ws)
{
    const float* L = ws + OFF_LC2;
    const float* G = ws + OFF_G;
    int c = blockIdx.x, l = threadIdx.x;
    int k0 = l, k1 = l + 64, k2 = l + 128;
    float x0 = 0, x1 = 0, x2 = 0, ss = 0;
    for (int i = 0; i < MM; i++) {
        const float* Lr = L + i * MM;
        float s = 0.0f;
        if (k0 < i) s = fmaf(Lr[k0], x0, s);
        if (k1 < i) s = fmaf(Lr[k1], x1, s);
        if (k2 < i) s = fmaf(Lr[k2], x2, s);
        #pragma unroll
        for (int off = 1; off < 64; off <<= 1) s += __shfl_xor(s, off);
        float xi = G[i * QD + c] - s;              // unit diagonal
        if (k0 == i) x0 = xi;
        if (k1 == i) x1 = xi;
        if (k2 == i) x2 = xi;
        if (l == 0) ss += xi * xi / Lr[i];         // / d_i (diag holds d)
    }
    if (l == 0) atomicAdd(&ws[OFF_SCAL + 2], ss);
}

// ---------------- misc scalar sums over X_mean / X_var ----------------------
__global__ void k_sums(const float* __restrict__ X_mean, const float* __restrict__ X_var,
                       float* __restrict__ ws)
{
    int idx = blockIdx.x * 256 + threadIdx.x;
    float pVo = 0, pMo = 0, pLg = 0, pMb = 0;
    if (idx < NTT * QD) {
        float xm = X_mean[idx], xv = X_var[idx];
        if (idx >= LT * QD) { pVo = xv; pMo = xm * xm; pLg = logf(xv); }
        else                { pMb = xm * xm + xv; }
    }
    pVo = bfly_sum(pVo); pMo = bfly_sum(pMo); pLg = bfly_sum(pLg); pMb = bfly_sum(pMb);
    __shared__ float part[4][4];
    if ((threadIdx.x & 63) == 0) {
        int w = threadIdx.x >> 6;
        part[w][0] = pVo; part[w][1] = pMo; part[w][2] = pLg; part[w][3] = pMb;
    }
    __syncthreads();
    if (threadIdx.x == 0) {
        #pragma unroll
        for (int t = 0; t < 4; t++)
            atomicAdd(&ws[OFF_SCAL + 3 + t],
                      part[0][t] + part[1][t] + part[2][t] + part[3][t]);
    }
}

// ---------------- final scalar assembly -------------------------------------
__global__ void k_final(const float* __restrict__ ws, const float* __restrict__ kern_var,
                        const float* __restrict__ lik, float* __restrict__ out)
{
    float kv = *kern_var, s2v = *lik;
    float inv_s2 = 1.0f / s2v;
    const float lp2pi = 1.8378770664093453f;  // log(2*pi)
    float trA  = ws[OFF_SCAL + 0] * inv_s2;                    // trace(AAT)
    float ldB  = 2.0f * (ws[OFF_SCAL + 8] - ws[OFF_SCAL + 7]); // logdetC2 - logdetKuu
    float sc2  = ws[OFF_SCAL + 2] * inv_s2 * inv_s2;           // sum(c^2)
    float Svo  = ws[OFF_SCAL + 3];
    float Smo2 = ws[OFF_SCAL + 4];
    float Slog = ws[OFF_SCAL + 5];
    float Smb  = ws[OFF_SCAL + 6];
    float ND = 18000.0f;   // (Nt-Lt)*D
    float Df = 12.0f;
    float bound = -0.5f * ND * (lp2pi + logf(s2v));
    bound += -0.5f * inv_s2 * (Svo + Smo2);
    bound += -0.5f * Df * ((kv * 1500.0f) * inv_s2 - trA);
    bound += -0.5f * Df * ldB;
    bound += 0.5f * sc2;
    bound += 0.5f * Slog + 0.5f * ND * lp2pi;      // ent
    bound += -96.0f * lp2pi - 0.5f * Smb;          // ent2 (Lt*D = 96)
    out[0] = bound;
}

extern "C" void kernel_launch(void* const* d_in, const int* in_sizes, int n_in,
                              void* d_out, int out_size, void* d_ws, size_t ws_size,
                              hipStream_t stream)
{
    const float* Xm_m    = (const float*)d_in[1];
    const float* Xm_v    = (const float*)d_in[2];
    const float* Z       = (const float*)d_in[3];
    const float* X_mean  = (const float*)d_in[4];
    const float* X_var   = (const float*)d_in[5];
    const float* kern_var= (const float*)d_in[6];
    const float* kern_ls = (const float*)d_in[7];
    const float* lik_var = (const float*)d_in[8];
    float* ws  = (float*)d_ws;
    float* out = (float*)d_out;

    // zero scalar slots + survivor counter + row-UB keys (contiguous)
    hipMemsetAsync(ws + OFF_SCAL, 0, (16 + NR) * sizeof(float), stream);

    k_prep<<<NR, 192, 0, stream>>>(Xm_m, Xm_v, X_mean, X_var, kern_ls, ws);
    k_zst<<<(MM * DIN + 255) / 256, 256, 0, stream>>>(Z, kern_ls, ws);
    k_kuu<<<(MM * MM + 255) / 256, 256, 0, stream>>>(kern_var, ws);
    k_psi1<<<dim3(94, 12), 256, 0, stream>>>(Z, kern_var, ws);
    k_bc<<<dim3(94, 12), 256, 0, stream>>>(Z, ws);           // F + rowUB (after psi1)
    k_g<<<MM, 256, 0, stream>>>(X_mean, ws);
    k_rowmax<<<(NR + 255) / 256, 256, 0, stream>>>(ws);      // compact survivors
    k_psi2<<<dim3(6, 6), 256, 0, stream>>>(Z, kern_var, ws); // fused finalize
    k_chol2<<<2, 256, 0, stream>>>(ws, lik_var);             // LDL^T: Lc, Lc2 + logdets
    k_trinv<<<MM, 64, 0, stream>>>(ws);                      // V = Lc^{-1}
    k_tracedot<<<MM, 256, 0, stream>>>(ws);                  // trace with 1/d_i
    k_solve12<<<QD, 64, 0, stream>>>(ws);                    // ||.||^2 with 1/d_i
    k_sums<<<(NTT * QD + 255) / 256, 256, 0, stream>>>(X_mean, X_var, ws);
    k_final<<<1, 1, 0, stream>>>(ws, kern_var, lik_var, out);
}

// Round 6
// 95.388 us; speedup vs baseline: 6.4591x; 6.4591x over previous
//
#include <hip/hip_runtime.h>
#include <math.h>

// Problem dims (fixed by setup_inputs)
#define NR   1500     // rows of X_m  (Nt - Lt)
#define NTT  1508     // Nt
#define QD   12       // D
#define LT   8
#define DIN  192      // 2*Lt*Q
#define MM   192      // M
#define JITTER 1e-6f
// Exact per-row suprema: psi1 expo <= logdet1[n], psi2 expo <= logdet2[n].
// Rows below this cut contribute < e^-30 ~ 1e-13 each -> provably < 1e-6 relative.
#define PRUNE_CUT -30.0f

// ---- workspace layout (float offsets) ----
#define OFF_W2    0
#define OFF_WU2   288000
#define OFF_P1    576000
#define OFF_F     576000      // alias: F overwrites P1 after k_psi1
#define OFF_R1    864000
#define OFF_S1    1152000
#define OFF_S2    1153500
#define OFF_ZST   1155000
#define OFF_V     1155000     // alias: V overwrites ZST after k_kuu
#define OFF_D2ZZ  1191864
#define OFF_KUU   1228728
#define OFF_PSI1  1265592
#define OFF_PSI2  1553592
#define OFF_LC    1590456
#define OFF_LC2   1627320
#define OFF_G     1664184
#define OFF_SCAL  1666488
#define OFF_NLIST 1666504     // 1500 ints: surviving-n list for psi2
// scal slots: 0 trace_raw, 2 ||Y||^2, 3 sum(X_vo), 4 sum(X_mo^2),
//             5 sum(log X_vo), 6 sum(X_mb^2+X_vb), 7 0.5*logdetKuu, 8 0.5*logdetC2,
//             12 cnt2 (psi2 survivors), 13 cnt1 (psi1 survivors), 14 gflag (G != 0)

__device__ __forceinline__ float wave_reduce(float s) {
    s += __shfl_down(s, 32); s += __shfl_down(s, 16); s += __shfl_down(s, 8);
    s += __shfl_down(s, 4);  s += __shfl_down(s, 2);  s += __shfl_down(s, 1);
    return s;
}
__device__ __forceinline__ float bfly_sum(float s) {
    s += __shfl_xor(s, 32); s += __shfl_xor(s, 16); s += __shfl_xor(s, 8);
    s += __shfl_xor(s, 4);  s += __shfl_xor(s, 2);  s += __shfl_xor(s, 1);
    return s;
}
__device__ __forceinline__ int rd_cnt(const float* ws, int slot) {
    return ((const int*)(ws + OFF_SCAL))[slot];
}

// ---------------- per-n prep: hankel rows, derived arrays, s1/s2, prune -----
__global__ __launch_bounds__(192) void k_prep(
    const float* __restrict__ Xm_m, const float* __restrict__ Xm_v,
    const float* __restrict__ X_mean, const float* __restrict__ X_var,
    const float* __restrict__ kern_ls, float* __restrict__ ws)
{
    int n = blockIdx.x;
    int q = threadIdx.x;  // 0..191
    float u, v;
    if (q < 96) {                      // X_mean[:Nt-1] hankel -> contiguous
        u = X_mean[n * QD + q]; v = X_var[n * QD + q];
    } else {                           // Xm_m[1:Nt] hankel -> contiguous
        int j = q - 96;
        u = Xm_m[(1 + n) * QD + j]; v = Xm_v[(1 + n) * QD + j];
    }
    float ls = kern_ls[q]; float l2 = ls * ls;
    float d1 = l2 + v, d2 = l2 + 2.0f * v;
    float i1 = 1.0f / d1, i2 = 1.0f / d2;
    ws[OFF_P1  + n * DIN + q] = u * i1;
    ws[OFF_R1  + n * DIN + q] = i1;
    ws[OFF_W2  + n * DIN + q] = i2;
    ws[OFF_WU2 + n * DIN + q] = u * i2;

    float v0 = log1pf(v / l2);          // -> logdet1 part
    float v1 = log1pf(2.0f * v / l2);   // -> logdet2 part
    float v2 = u * u * i1;              // -> -0.5*sum u^2/d1
    float v3 = u * u * i2;              // -> a[n]
    v0 = bfly_sum(v0); v1 = bfly_sum(v1); v2 = bfly_sum(v2); v3 = bfly_sum(v3);
    __shared__ float part[3][4];
    if ((q & 63) == 0) {
        int w = q >> 6;
        part[w][0] = v0; part[w][1] = v1; part[w][2] = v2; part[w][3] = v3;
    }
    __syncthreads();
    if (q == 0) {
        float S0 = part[0][0] + part[1][0] + part[2][0];
        float S1 = part[0][1] + part[1][1] + part[2][1];
        float S2 = part[0][2] + part[1][2] + part[2][2];
        float S3 = part[0][3] + part[1][3] + part[2][3];
        ws[OFF_S1 + n] = -0.5f * (S0 + S2);
        ws[OFF_S2 + n] = -0.5f * S1 - S3;
        float ld1 = -0.5f * S0;          // exact sup of psi1 exponent
        float ld2 = -0.5f * S1;          // exact sup of psi2 exponent
        int* cnts = (int*)(ws + OFF_SCAL);
        if (ld1 > PRUNE_CUT) atomicAdd(&cnts[13], 1);
        if (ld2 > PRUNE_CUT) {
            int idx = atomicAdd(&cnts[12], 1);
            ((int*)(ws + OFF_NLIST))[idx] = n;
        }
    }
}

// ---------------- Zs transposed (only if Kuu needed) ------------------------
__global__ void k_zst(const float* __restrict__ Z, const float* __restrict__ kern_ls,
                      float* __restrict__ ws)
{
    if (rd_cnt(ws, 12) == 0 && rd_cnt(ws, 14) == 0) return;
    int idx = blockIdx.x * 256 + threadIdx.x;
    if (idx >= MM * DIN) return;
    int q = idx / MM, p = idx - q * MM;
    ws[OFF_ZST + idx] = Z[p * DIN + q] / kern_ls[q];
}

// ---------------- d2zz + Kuu (only if factorization needed) -----------------
__global__ void k_kuu(const float* __restrict__ kern_var, float* __restrict__ ws)
{
    if (rd_cnt(ws, 12) == 0 && rd_cnt(ws, 14) == 0) return;
    int idx = blockIdx.x * 256 + threadIdx.x;
    if (idx >= MM * MM) return;
    int m = idx / MM, p = idx - m * MM;
    const float* zst = ws + OFF_ZST;
    float d = 0.0f;
    for (int q = 0; q < DIN; q++) {
        float a = zst[q * MM + m], b = zst[q * MM + p];
        float t = a - b; d = fmaf(t, t, d);
    }
    ws[OFF_D2ZZ + idx] = d;
    float kv = *kern_var;
    ws[OFF_KUU + idx] = kv * __expf(-0.5f * d) + ((m == p) ? JITTER : 0.0f);
}

// ---------------- psi1 (1500 x 192), tiled; gated on cnt1 -------------------
__global__ __launch_bounds__(256) void k_psi1(
    const float* __restrict__ Z, const float* __restrict__ kern_var,
    float* __restrict__ ws)
{
    if (rd_cnt(ws, 13) == 0) return;
    int tx = threadIdx.x & 15, ty = threadIdx.x >> 4;
    int n = blockIdx.x * 16 + ty;
    int m = blockIdx.y * 16 + tx;
    __shared__ float Ps[16][17], Rs[16][17], Zs[16][17], Z2s[16][17];
    float dot1 = 0.0f, dot2 = 0.0f;
    for (int qc = 0; qc < 12; qc++) {
        int q0 = qc * 16;
        Ps[ty][tx] = (n < NR) ? ws[OFF_P1 + n * DIN + q0 + tx] : 0.0f;
        Rs[ty][tx] = (n < NR) ? ws[OFF_R1 + n * DIN + q0 + tx] : 0.0f;
        float z = Z[(blockIdx.y * 16 + ty) * DIN + q0 + tx];
        Zs[ty][tx] = z; Z2s[ty][tx] = z * z;
        __syncthreads();
        #pragma unroll
        for (int k = 0; k < 16; k++) {
            dot1 = fmaf(Ps[ty][k], Zs[tx][k], dot1);
            dot2 = fmaf(Rs[ty][k], Z2s[tx][k], dot2);
        }
        __syncthreads();
    }
    if (n < NR) {
        float kv = *kern_var;
        ws[OFF_PSI1 + n * MM + m] = kv * __expf(ws[OFF_S1 + n] + dot1 - 0.5f * dot2);
    }
}

// ---------------- G = psi1^T @ X_mo; set gflag if any nonzero ---------------
__global__ __launch_bounds__(256) void k_g(const float* __restrict__ X_mean,
                                           float* __restrict__ ws)
{
    if (rd_cnt(ws, 13) == 0) return;   // psi1 identically 0 -> G stays 0 (memset)
    int m = blockIdx.x, tid = threadIdx.x;
    const float* psi1 = ws + OFF_PSI1;
    float g[QD];
    #pragma unroll
    for (int d = 0; d < QD; d++) g[d] = 0.0f;
    for (int n = tid; n < NR; n += 256) {
        float p = psi1[n * MM + m];
        const float* xr = X_mean + (LT + n) * QD;
        #pragma unroll
        for (int d = 0; d < QD; d++) g[d] = fmaf(p, xr[d], g[d]);
    }
    __shared__ float red[256];
    bool any = false;
    for (int d = 0; d < QD; d++) {
        red[tid] = g[d]; __syncthreads();
        if (tid < 128) red[tid] += red[tid + 128];
        __syncthreads();
        if (tid < 64) {
            float s = red[tid] + red[tid + 64];
            s = wave_reduce(s);
            if (tid == 0) { ws[OFF_G + m * QD + d] = s; any |= (s != 0.0f); }
        }
        __syncthreads();
    }
    if (tid == 0 && any) atomicOr((int*)(ws + OFF_SCAL) + 14, 1);
}

// ---- F[n,m] = b - 0.25c (psi2 separable part); gated on cnt2 ---------------
__global__ __launch_bounds__(256) void k_bc(
    const float* __restrict__ Z, float* __restrict__ ws)
{
    if (rd_cnt(ws, 12) == 0) return;
    int tx = threadIdx.x & 15, ty = threadIdx.x >> 4;
    int n = blockIdx.x * 16 + ty;
    int m = blockIdx.y * 16 + tx;
    __shared__ float Us[16][17], Ws[16][17], Zs[16][17];
    float dotB = 0.0f, dotC = 0.0f;
    for (int qc = 0; qc < 12; qc++) {
        int q0 = qc * 16;
        Us[ty][tx] = (n < NR) ? ws[OFF_WU2 + n * DIN + q0 + tx] : 0.0f;
        Ws[ty][tx] = (n < NR) ? ws[OFF_W2  + n * DIN + q0 + tx] : 0.0f;
        Zs[ty][tx] = Z[(blockIdx.y * 16 + ty) * DIN + q0 + tx];
        __syncthreads();
        #pragma unroll
        for (int k = 0; k < 16; k++) {
            float z = Zs[tx][k];
            dotB = fmaf(z, Us[ty][k], dotB);
            dotC = fmaf(z * z, Ws[ty][k], dotC);
        }
        __syncthreads();
    }
    if (n < NR) ws[OFF_F + n * MM + m] = fmaf(-0.25f, dotC, dotB);
}

// ---------------- psi2: sum over surviving n, finalize fused ----------------
#define ZR 196   // LDS row stride
__global__ __launch_bounds__(256) void k_psi2(
    const float* __restrict__ Z, const float* __restrict__ kern_var,
    float* __restrict__ ws)
{
    int count = rd_cnt(ws, 12);
    int gflag = rd_cnt(ws, 14);
    int tx = threadIdx.x & 15, ty = threadIdx.x >> 4;
    int m0 = blockIdx.x * 32, p0 = blockIdx.y * 32;
    int mA = m0 + 2 * ty, pA = p0 + 2 * tx;
    float* P2 = ws + OFF_PSI2;
    if (count == 0) {
        if (gflag != 0) {   // chol2 will read psi2: provide exact zeros
            P2[(mA    ) * MM + pA    ] = 0.0f;
            P2[(mA    ) * MM + pA + 1] = 0.0f;
            P2[(mA + 1) * MM + pA    ] = 0.0f;
            P2[(mA + 1) * MM + pA + 1] = 0.0f;
        }
        return;
    }
    float a00 = 0, a01 = 0, a10 = 0, a11 = 0;
    {
        __shared__ __align__(16) float Zm[32 * ZR], Zp[32 * ZR];
        for (int idx = threadIdx.x; idx < 32 * DIN; idx += 256) {
            int r = idx / DIN, q = idx - r * DIN;
            Zm[r * ZR + q] = Z[(m0 + r) * DIN + q];
            Zp[r * ZR + q] = Z[(p0 + r) * DIN + q];
        }
        __syncthreads();
        const float* w2base = ws + OFF_W2;
        const float* F      = ws + OFF_F;
        const float* s2arr  = ws + OFF_S2;
        const int* list     = (const int*)(ws + OFF_NLIST);
        const float4* zm0 = (const float4*)(Zm + (2 * ty    ) * ZR);
        const float4* zm1 = (const float4*)(Zm + (2 * ty + 1) * ZR);
        const float4* zp0 = (const float4*)(Zp + (2 * tx    ) * ZR);
        const float4* zp1 = (const float4*)(Zp + (2 * tx + 1) * ZR);
        for (int li = 0; li < count; li++) {
            int n = list[li];
            const float4* w2p = (const float4*)(w2base + n * DIN);
            float e00 = 0, e01 = 0, e10 = 0, e11 = 0;
            #pragma unroll 4
            for (int g = 0; g < DIN / 4; g++) {
                float4 w  = w2p[g];
                float4 a  = zm0[g], b = zm1[g], c = zp0[g], d = zp1[g];
                float wp0, wp1;
                wp0 = w.x * c.x; wp1 = w.x * d.x;
                e00 = fmaf(a.x, wp0, e00); e01 = fmaf(a.x, wp1, e01);
                e10 = fmaf(b.x, wp0, e10); e11 = fmaf(b.x, wp1, e11);
                wp0 = w.y * c.y; wp1 = w.y * d.y;
                e00 = fmaf(a.y, wp0, e00); e01 = fmaf(a.y, wp1, e01);
                e10 = fmaf(b.y, wp0, e10); e11 = fmaf(b.y, wp1, e11);
                wp0 = w.z * c.z; wp1 = w.z * d.z;
                e00 = fmaf(a.z, wp0, e00); e01 = fmaf(a.z, wp1, e01);
                e10 = fmaf(b.z, wp0, e10); e11 = fmaf(b.z, wp1, e11);
                wp0 = w.w * c.w; wp1 = w.w * d.w;
                e00 = fmaf(a.w, wp0, e00); e01 = fmaf(a.w, wp1, e01);
                e10 = fmaf(b.w, wp0, e10); e11 = fmaf(b.w, wp1, e11);
            }
            float s2n = s2arr[n];
            float Fm0 = F[n * MM + mA], Fm1 = F[n * MM + mA + 1];
            float Fp0 = F[n * MM + pA], Fp1 = F[n * MM + pA + 1];
            a00 += __expf(s2n + Fm0 + Fp0 - 0.5f * e00);
            a01 += __expf(s2n + Fm0 + Fp1 - 0.5f * e01);
            a10 += __expf(s2n + Fm1 + Fp0 - 0.5f * e10);
            a11 += __expf(s2n + Fm1 + Fp1 - 0.5f * e11);
        }
    }
    float kv = *kern_var; float kv2 = kv * kv;
    const float* dz = ws + OFF_D2ZZ;
    P2[(mA    ) * MM + pA    ] = kv2 * __expf(-0.25f * dz[(mA    ) * MM + pA    ]) * a00;
    P2[(mA    ) * MM + pA + 1] = kv2 * __expf(-0.25f * dz[(mA    ) * MM + pA + 1]) * a01;
    P2[(mA + 1) * MM + pA    ] = kv2 * __expf(-0.25f * dz[(mA + 1) * MM + pA    ]) * a10;
    P2[(mA + 1) * MM + pA + 1] = kv2 * __expf(-0.25f * dz[(mA + 1) * MM + pA + 1]) * a11;
}

// ---------------- dual blocked LDL^T (block 0: Kuu, block 1: C2) ------------
#define ALD 196
#define NB  32
__global__ __launch_bounds__(256) void k_chol2(float* __restrict__ ws,
                                               const float* __restrict__ lik)
{
    if (rd_cnt(ws, 12) == 0 && rd_cnt(ws, 14) == 0) return;  // ldB=0, trace=0, c=0
    __shared__ __align__(16) float A[MM * ALD];
    int tid = threadIdx.x;
    bool isC2 = (blockIdx.x == 1);
    const float* Kuu  = ws + OFF_KUU;
    const float* psi2 = ws + OFF_PSI2;
    float inv_s2 = 1.0f / (*lik);
    for (int idx = tid; idx < MM * MM; idx += 256) {
        int i = idx / MM, j = idx - i * MM;
        float v = Kuu[idx];
        if (isC2) v = fmaf(psi2[idx], inv_s2, v);
        A[i * ALD + j] = v;
    }
    __syncthreads();

    float logacc = 0.0f;
    int ty = tid >> 4, tx = tid & 15;
    for (int p = 0; p < MM / NB; p++) {
        int k0 = p * NB;
        int e  = k0 + NB;
        if (tid < 64) {
            int lane = tid;
            float P[3][NB];
            #pragma unroll
            for (int s = 0; s < 3; s++) {
                int r = lane + 64 * s;
                #pragma unroll
                for (int g = 0; g < NB / 4; g++) {
                    float4 v = *(const float4*)&A[r * ALD + k0 + 4 * g];
                    P[s][4*g] = v.x; P[s][4*g+1] = v.y; P[s][4*g+2] = v.z; P[s][4*g+3] = v.w;
                }
            }
            int sD = k0 >> 6;
            int lD = k0 & 63;
            #pragma unroll
            for (int c = 0; c < NB; c++) {
                int k = k0 + c;
                float colc = (sD == 0) ? P[0][c] : ((sD == 1) ? P[1][c] : P[2][c]);
                float dkk = __shfl(colc, lD + c);
                float inv = 1.0f / dkk;
                logacc += logf(dkk);
                float m0 = (lane       > k) ? P[0][c] * inv : 0.0f;
                float m1 = (lane + 64  > k) ? P[1][c] * inv : 0.0f;
                float m2 = (lane + 128 > k) ? P[2][c] * inv : 0.0f;
                P[0][c] = (lane       > k) ? m0 : P[0][c];
                P[1][c] = (lane + 64  > k) ? m1 : P[1][c];
                P[2][c] = (lane + 128 > k) ? m2 : P[2][c];
                #pragma unroll
                for (int j = c + 1; j < NB; j++) {
                    float w = __shfl(colc, lD + j);
                    P[0][j] = fmaf(-m0, w, P[0][j]);
                    P[1][j] = fmaf(-m1, w, P[1][j]);
                    P[2][j] = fmaf(-m2, w, P[2][j]);
                }
            }
            #pragma unroll
            for (int s = 0; s < 3; s++) {
                int r = lane + 64 * s;
                #pragma unroll
                for (int g = 0; g < NB / 4; g++) {
                    float4 v = make_float4(P[s][4*g], P[s][4*g+1], P[s][4*g+2], P[s][4*g+3]);
                    *(float4*)&A[r * ALD + k0 + 4 * g] = v;
                }
            }
        }
        __syncthreads();
        int T = MM - e;
        if (T > 0) {
            for (int idx = tid; idx < NB * T; idx += 256) {
                int c = idx / T, j = e + (idx - c * T);
                float d = A[(k0 + c) * ALD + (k0 + c)];
                A[(k0 + c) * ALD + j] = A[j * ALD + k0 + c] * sqrtf(d);
            }
            __syncthreads();
            int nT = (T + 127) / 128;
            for (int bi = 0; bi < nT; bi++)
            for (int bj = 0; bj < nT; bj++) {
                int i0 = e + 128 * bi + 8 * ty;
                int j0 = e + 128 * bj + 8 * tx;
                int ic = (i0 < MM - 8) ? i0 : (MM - 8);
                int jc = (j0 < MM - 8) ? j0 : (MM - 8);
                float4 acc[8][2];
                #pragma unroll
                for (int r = 0; r < 8; r++) {
                    acc[r][0] = *(const float4*)&A[(ic + r) * ALD + jc];
                    acc[r][1] = *(const float4*)&A[(ic + r) * ALD + jc + 4];
                }
                #pragma unroll 4
                for (int c = 0; c < NB; c++) {
                    const float* row = &A[(k0 + c) * ALD];
                    float4 av0 = *(const float4*)&row[ic];
                    float4 av1 = *(const float4*)&row[ic + 4];
                    float4 bv0 = *(const float4*)&row[jc];
                    float4 bv1 = *(const float4*)&row[jc + 4];
                    float avs[8] = {av0.x, av0.y, av0.z, av0.w, av1.x, av1.y, av1.z, av1.w};
                    #pragma unroll
                    for (int r = 0; r < 8; r++) {
                        float a = avs[r];
                        acc[r][0].x = fmaf(-a, bv0.x, acc[r][0].x);
                        acc[r][0].y = fmaf(-a, bv0.y, acc[r][0].y);
                        acc[r][0].z = fmaf(-a, bv0.z, acc[r][0].z);
                        acc[r][0].w = fmaf(-a, bv0.w, acc[r][0].w);
                        acc[r][1].x = fmaf(-a, bv1.x, acc[r][1].x);
                        acc[r][1].y = fmaf(-a, bv1.y, acc[r][1].y);
                        acc[r][1].z = fmaf(-a, bv1.z, acc[r][1].z);
                        acc[r][1].w = fmaf(-a, bv1.w, acc[r][1].w);
                    }
                }
                if (ic == i0 && jc == j0) {
                    #pragma unroll
                    for (int r = 0; r < 8; r++) {
                        *(float4*)&A[(i0 + r) * ALD + j0]     = acc[r][0];
                        *(float4*)&A[(i0 + r) * ALD + j0 + 4] = acc[r][1];
                    }
                }
            }
            __syncthreads();
        }
    }
    float* dst = ws + (isC2 ? OFF_LC2 : OFF_LC);
    for (int idx = tid; idx < MM * MM; idx += 256) {
        int i = idx / MM, j = idx - i * MM;
        dst[idx] = A[i * ALD + j];
    }
    if (tid == 0) ws[OFF_SCAL + (isC2 ? 8 : 7)] = 0.5f * logacc;
}

// ---------------- V = L^{-1} (unit-lower); only if psi2 nonzero -------------
__global__ __launch_bounds__(64) void k_trinv(float* __restrict__ ws)
{
    if (rd_cnt(ws, 12) == 0) return;
    const float* L = ws + OFF_LC;
    float* V = ws + OFF_V;
    int j = blockIdx.x, l = threadIdx.x;
    int k0 = j + l, k1 = k0 + 64, k2 = k0 + 128;
    float x0 = 0, x1 = 0, x2 = 0;
    for (int i = j; i < MM; i++) {
        const float* Lr = L + i * MM;
        float s = 0.0f;
        if (k0 < i) s = fmaf(Lr[k0], x0, s);
        if (k1 < i) s = fmaf(Lr[k1], x1, s);
        if (k2 < i) s = fmaf(Lr[k2], x2, s);
        #pragma unroll
        for (int off = 1; off < 64; off <<= 1) s += __shfl_xor(s, off);
        float xi = ((i == j) ? 1.0f : 0.0f) - s;
        if (k0 == i) x0 = xi;
        if (k1 == i) x1 = xi;
        if (k2 == i) x2 = xi;
        if (l == 0) V[i * MM + j] = xi;
    }
}

// -------- trace_raw = sum_i (V[i,:] psi2 V[i,:]^T) / d_i --------------------
__global__ __launch_bounds__(256) void k_tracedot(float* __restrict__ ws)
{
    if (rd_cnt(ws, 12) == 0) return;    // psi2 == 0 -> trace 0
    int i = blockIdx.x, tid = threadIdx.x;
    __shared__ float vrow[MM];
    const float* V = ws + OFF_V;
    const float* P = ws + OFF_PSI2;
    for (int a = tid; a < MM; a += 256) vrow[a] = (a <= i) ? V[i * MM + a] : 0.0f;
    __syncthreads();
    float acc = 0.0f;
    for (int a = tid; a <= i; a += 256) {
        const float* Pr = P + a * MM;
        float inner = 0.0f;
        for (int b = 0; b <= i; b++) inner = fmaf(Pr[b], vrow[b], inner);
        acc = fmaf(vrow[a], inner, acc);
    }
    __shared__ float red[256];
    red[tid] = acc; __syncthreads();
    if (tid < 128) red[tid] += red[tid + 128];
    __syncthreads();
    if (tid < 64) {
        float s = red[tid] + red[tid + 64];
        s = wave_reduce(s);
        if (tid == 0) {
            float di = ws[OFF_LC + i * MM + i];   // LDL diagonal
            atomicAdd(&ws[OFF_SCAL + 0], s / di);
        }
    }
}

// ------ Y = L2^{-1} G (unit-lower, 12 RHS); only if G nonzero ---------------
__global__ __launch_bounds__(64) void k_solve12(float* __restrict__ ws)
{
    if (rd_cnt(ws, 14) == 0) return;    // G == 0 -> ||Y||^2 = 0
    const float* L = ws + OFF_LC2;
    const float* G = ws + OFF_G;
    int c = blockIdx.x, l = threadIdx.x;
    int k0 = l, k1 = l + 64, k2 = l + 128;
    float x0 = 0, x1 = 0, x2 = 0, ss = 0;
    for (int i = 0; i < MM; i++) {
        const float* Lr = L + i * MM;
        float s = 0.0f;
        if (k0 < i) s = fmaf(Lr[k0], x0, s);
        if (k1 < i) s = fmaf(Lr[k1], x1, s);
        if (k2 < i) s = fmaf(Lr[k2], x2, s);
        #pragma unroll
        for (int off = 1; off < 64; off <<= 1) s += __shfl_xor(s, off);
        float xi = G[i * QD + c] - s;
        if (k0 == i) x0 = xi;
        if (k1 == i) x1 = xi;
        if (k2 == i) x2 = xi;
        if (l == 0) ss += xi * xi / Lr[i];
    }
    if (l == 0) atomicAdd(&ws[OFF_SCAL + 2], ss);
}

// ---------------- misc scalar sums over X_mean / X_var ----------------------
__global__ void k_sums(const float* __restrict__ X_mean, const float* __restrict__ X_var,
                       float* __restrict__ ws)
{
    int idx = blockIdx.x * 256 + threadIdx.x;
    float pVo = 0, pMo = 0, pLg = 0, pMb = 0;
    if (idx < NTT * QD) {
        float xm = X_mean[idx], xv = X_var[idx];
        if (idx >= LT * QD) { pVo = xv; pMo = xm * xm; pLg = logf(xv); }
        else                { pMb = xm * xm + xv; }
    }
    pVo = bfly_sum(pVo); pMo = bfly_sum(pMo); pLg = bfly_sum(pLg); pMb = bfly_sum(pMb);
    __shared__ float part[4][4];
    if ((threadIdx.x & 63) == 0) {
        int w = threadIdx.x >> 6;
        part[w][0] = pVo; part[w][1] = pMo; part[w][2] = pLg; part[w][3] = pMb;
    }
    __syncthreads();
    if (threadIdx.x == 0) {
        #pragma unroll
        for (int t = 0; t < 4; t++)
            atomicAdd(&ws[OFF_SCAL + 3 + t],
                      part[0][t] + part[1][t] + part[2][t] + part[3][t]);
    }
}

// ---------------- final scalar assembly -------------------------------------
__global__ void k_final(const float* __restrict__ ws, const float* __restrict__ kern_var,
                        const float* __restrict__ lik, float* __restrict__ out)
{
    float kv = *kern_var, s2v = *lik;
    float inv_s2 = 1.0f / s2v;
    const float lp2pi = 1.8378770664093453f;  // log(2*pi)
    float trA  = ws[OFF_SCAL + 0] * inv_s2;                    // trace(AAT)
    float ldB  = 2.0f * (ws[OFF_SCAL + 8] - ws[OFF_SCAL + 7]); // logdetC2 - logdetKuu
    float sc2  = ws[OFF_SCAL + 2] * inv_s2 * inv_s2;           // sum(c^2)
    float Svo  = ws[OFF_SCAL + 3];
    float Smo2 = ws[OFF_SCAL + 4];
    float Slog = ws[OFF_SCAL + 5];
    float Smb  = ws[OFF_SCAL + 6];
    float ND = 18000.0f;   // (Nt-Lt)*D
    float Df = 12.0f;
    float bound = -0.5f * ND * (lp2pi + logf(s2v));
    bound += -0.5f * inv_s2 * (Svo + Smo2);
    bound += -0.5f * Df * ((kv * 1500.0f) * inv_s2 - trA);
    bound += -0.5f * Df * ldB;
    bound += 0.5f * sc2;
    bound += 0.5f * Slog + 0.5f * ND * lp2pi;      // ent
    bound += -96.0f * lp2pi - 0.5f * Smb;          // ent2 (Lt*D = 96)
    out[0] = bound;
}

extern "C" void kernel_launch(void* const* d_in, const int* in_sizes, int n_in,
                              void* d_out, int out_size, void* d_ws, size_t ws_size,
                              hipStream_t stream)
{
    const float* Xm_m    = (const float*)d_in[1];
    const float* Xm_v    = (const float*)d_in[2];
    const float* Z       = (const float*)d_in[3];
    const float* X_mean  = (const float*)d_in[4];
    const float* X_var   = (const float*)d_in[5];
    const float* kern_var= (const float*)d_in[6];
    const float* kern_ls = (const float*)d_in[7];
    const float* lik_var = (const float*)d_in[8];
    float* ws  = (float*)d_ws;
    float* out = (float*)d_out;

    // zero G + scalar slots/flags (contiguous region)
    hipMemsetAsync(ws + OFF_G, 0, (MM * QD + 16) * sizeof(float), stream);

    k_prep<<<NR, 192, 0, stream>>>(Xm_m, Xm_v, X_mean, X_var, kern_ls, ws);
    k_psi1<<<dim3(94, 12), 256, 0, stream>>>(Z, kern_var, ws);   // gated cnt1
    k_g<<<MM, 256, 0, stream>>>(X_mean, ws);                     // gated cnt1; sets gflag
    k_zst<<<(MM * DIN + 255) / 256, 256, 0, stream>>>(Z, kern_ls, ws);   // gated
    k_kuu<<<(MM * MM + 255) / 256, 256, 0, stream>>>(kern_var, ws);      // gated
    k_bc<<<dim3(94, 12), 256, 0, stream>>>(Z, ws);               // gated cnt2
    k_psi2<<<dim3(6, 6), 256, 0, stream>>>(Z, kern_var, ws);     // gated cnt2/gflag
    k_chol2<<<2, 256, 0, stream>>>(ws, lik_var);                 // gated cnt2|gflag
    k_trinv<<<MM, 64, 0, stream>>>(ws);                          // gated cnt2
    k_tracedot<<<MM, 256, 0, stream>>>(ws);                      // gated cnt2
    k_solve12<<<QD, 64, 0, stream>>>(ws);                        // gated gflag
    k_sums<<<(NTT * QD + 255) / 256, 256, 0, stream>>>(X_mean, X_var, ws);
    k_final<<<1, 1, 0, stream>>>(ws, kern_var, lik_var, out);
}

// Round 7
// 92.647 us; speedup vs baseline: 6.6502x; 1.0296x over previous
//
#include <hip/hip_runtime.h>
#include <math.h>

// Problem dims (fixed by setup_inputs)
#define NR   1500     // rows of X_m  (Nt - Lt)
#define NTT  1508     // Nt
#define QD   12       // D
#define LT   8
#define DIN  192      // 2*Lt*Q
#define MM   192      // M
#define JITTER 1e-6f
// Exact per-row suprema: psi1 expo <= logdet1[n], psi2 expo <= logdet2[n].
// Rows below this cut contribute < e^-30 ~ 1e-13 each -> provably < 1e-6 relative.
#define PRUNE_CUT -30.0f

// ---- workspace layout (float offsets) ----
#define OFF_W2    0
#define OFF_WU2   288000
#define OFF_P1    576000
#define OFF_F     576000      // alias: F overwrites P1 after psi1 phase
#define OFF_R1    864000
#define OFF_S1    1152000
#define OFF_S2    1153500
#define OFF_V     1155000
#define OFF_D2ZZ  1191864
#define OFF_KUU   1228728
#define OFF_PSI1  1265592
#define OFF_PSI2  1553592
#define OFF_LC    1590456
#define OFF_LC2   1627320
#define OFF_G     1664184
#define OFF_SCAL  1666488
#define OFF_NLIST 1666504     // 1500 ints: surviving-n list for psi2
// scal slots: 0 trace_raw, 2 ||Y||^2, 3 sum(X_vo), 4 sum(X_mo^2),
//             5 sum(log X_vo), 6 sum(X_mb^2+X_vb), 7 0.5*logdetKuu, 8 0.5*logdetC2,
//             12 cnt2 (psi2 survivors), 13 cnt1 (psi1 survivors), 14 gflag (G != 0),
//             15 ticket (sumsfinal last-block)

__device__ __forceinline__ float wave_reduce(float s) {
    s += __shfl_down(s, 32); s += __shfl_down(s, 16); s += __shfl_down(s, 8);
    s += __shfl_down(s, 4);  s += __shfl_down(s, 2);  s += __shfl_down(s, 1);
    return s;
}
__device__ __forceinline__ float bfly_sum(float s) {
    s += __shfl_xor(s, 32); s += __shfl_xor(s, 16); s += __shfl_xor(s, 8);
    s += __shfl_xor(s, 4);  s += __shfl_xor(s, 2);  s += __shfl_xor(s, 1);
    return s;
}
__device__ __forceinline__ int rd_cnt(const float* ws, int slot) {
    return ((const int*)(ws + OFF_SCAL))[slot];
}

// ---- per-n prep: wave-per-n, shfl-only reductions, derived arrays, prune ---
__global__ __launch_bounds__(256) void k_prep(
    const float* __restrict__ Xm_m, const float* __restrict__ Xm_v,
    const float* __restrict__ X_mean, const float* __restrict__ X_var,
    const float* __restrict__ kern_ls, float* __restrict__ ws)
{
    int wave = threadIdx.x >> 6, lane = threadIdx.x & 63;
    int n = blockIdx.x * 4 + wave;            // 1500 = 375*4 exact
    float v0 = 0, v1 = 0, v2 = 0, v3 = 0;
    #pragma unroll
    for (int s = 0; s < 3; s++) {
        int q = lane + 64 * s;
        float u, v;
        if (q < 96) {                          // X_mean[:Nt-1] hankel (contiguous)
            u = X_mean[n * QD + q]; v = X_var[n * QD + q];
        } else {                               // Xm_m[1:Nt] hankel (contiguous)
            int j = q - 96;
            u = Xm_m[(1 + n) * QD + j]; v = Xm_v[(1 + n) * QD + j];
        }
        float ls = kern_ls[q]; float l2 = ls * ls;
        float d1 = l2 + v, d2 = l2 + 2.0f * v;
        float i1 = 1.0f / d1, i2 = 1.0f / d2;
        ws[OFF_P1  + n * DIN + q] = u * i1;
        ws[OFF_R1  + n * DIN + q] = i1;
        ws[OFF_W2  + n * DIN + q] = i2;
        ws[OFF_WU2 + n * DIN + q] = u * i2;
        v0 += log1pf(v / l2);
        v1 += log1pf(2.0f * v / l2);
        v2 += u * u * i1;
        v3 += u * u * i2;
    }
    v0 = bfly_sum(v0); v1 = bfly_sum(v1); v2 = bfly_sum(v2); v3 = bfly_sum(v3);
    if (lane == 0) {
        ws[OFF_S1 + n] = -0.5f * (v0 + v2);
        ws[OFF_S2 + n] = -0.5f * v1 - v3;
        float ld1 = -0.5f * v0;                // exact sup of psi1 exponent
        float ld2 = -0.5f * v1;                // exact sup of psi2 exponent
        int* cnts = (int*)(ws + OFF_SCAL);
        if (ld1 > PRUNE_CUT) atomicAdd(&cnts[13], 1);
        if (ld2 > PRUNE_CUT) {
            int idx = atomicAdd(&cnts[12], 1);
            ((int*)(ws + OFF_NLIST))[idx] = n;
        }
    }
}

// ---- merged: z=0 -> psi1 (gate cnt1); z=1 -> F = b-0.25c (gate cnt2) -------
__global__ __launch_bounds__(256) void k_psi1bc(
    const float* __restrict__ Z, const float* __restrict__ kern_var,
    float* __restrict__ ws)
{
    int tx = threadIdx.x & 15, ty = threadIdx.x >> 4;
    int n = blockIdx.x * 16 + ty;
    int m = blockIdx.y * 16 + tx;
    if (blockIdx.z == 0) {
        if (rd_cnt(ws, 13) == 0) return;
        __shared__ float Ps[16][17], Rs[16][17], Zs[16][17], Z2s[16][17];
        float dot1 = 0.0f, dot2 = 0.0f;
        for (int qc = 0; qc < 12; qc++) {
            int q0 = qc * 16;
            Ps[ty][tx] = (n < NR) ? ws[OFF_P1 + n * DIN + q0 + tx] : 0.0f;
            Rs[ty][tx] = (n < NR) ? ws[OFF_R1 + n * DIN + q0 + tx] : 0.0f;
            float z = Z[(blockIdx.y * 16 + ty) * DIN + q0 + tx];
            Zs[ty][tx] = z; Z2s[ty][tx] = z * z;
            __syncthreads();
            #pragma unroll
            for (int k = 0; k < 16; k++) {
                dot1 = fmaf(Ps[ty][k], Zs[tx][k], dot1);
                dot2 = fmaf(Rs[ty][k], Z2s[tx][k], dot2);
            }
            __syncthreads();
        }
        if (n < NR) {
            float kv = *kern_var;
            ws[OFF_PSI1 + n * MM + m] = kv * __expf(ws[OFF_S1 + n] + dot1 - 0.5f * dot2);
        }
    } else {
        if (rd_cnt(ws, 12) == 0) return;
        __shared__ float Us[16][17], Ws[16][17], Zb[16][17];
        float dotB = 0.0f, dotC = 0.0f;
        for (int qc = 0; qc < 12; qc++) {
            int q0 = qc * 16;
            Us[ty][tx] = (n < NR) ? ws[OFF_WU2 + n * DIN + q0 + tx] : 0.0f;
            Ws[ty][tx] = (n < NR) ? ws[OFF_W2  + n * DIN + q0 + tx] : 0.0f;
            Zb[ty][tx] = Z[(blockIdx.y * 16 + ty) * DIN + q0 + tx];
            __syncthreads();
            #pragma unroll
            for (int k = 0; k < 16; k++) {
                float z = Zb[tx][k];
                dotB = fmaf(z, Us[ty][k], dotB);
                dotC = fmaf(z * z, Ws[ty][k], dotC);
            }
            __syncthreads();
        }
        if (n < NR) ws[OFF_F + n * MM + m] = fmaf(-0.25f, dotC, dotB);
    }
}

// ---- merged: blocks 0..191 -> G row m (gate cnt1, sets gflag);
//      blocks 192..335 -> d2zz+Kuu 16x16 tile (gate cnt1|cnt2) ---------------
__global__ __launch_bounds__(256) void k_gkuu(
    const float* __restrict__ Z, const float* __restrict__ kern_ls,
    const float* __restrict__ kern_var, const float* __restrict__ X_mean,
    float* __restrict__ ws)
{
    if (blockIdx.x < MM) {
        if (rd_cnt(ws, 13) == 0) return;       // psi1 == 0 -> G stays 0 (memset)
        int m = blockIdx.x, tid = threadIdx.x;
        const float* psi1 = ws + OFF_PSI1;
        float g[QD];
        #pragma unroll
        for (int d = 0; d < QD; d++) g[d] = 0.0f;
        for (int n = tid; n < NR; n += 256) {
            float p = psi1[n * MM + m];
            const float* xr = X_mean + (LT + n) * QD;
            #pragma unroll
            for (int d = 0; d < QD; d++) g[d] = fmaf(p, xr[d], g[d]);
        }
        __shared__ float red[256];
        bool any = false;
        for (int d = 0; d < QD; d++) {
            red[tid] = g[d]; __syncthreads();
            if (tid < 128) red[tid] += red[tid + 128];
            __syncthreads();
            if (tid < 64) {
                float s = red[tid] + red[tid + 64];
                s = wave_reduce(s);
                if (tid == 0) { ws[OFF_G + m * QD + d] = s; any |= (s != 0.0f); }
            }
            __syncthreads();
        }
        if (tid == 0 && any) atomicOr((int*)(ws + OFF_SCAL) + 14, 1);
    } else {
        // Kuu needed if any downstream factorization might run (gflag => cnt1)
        if (rd_cnt(ws, 12) == 0 && rd_cnt(ws, 13) == 0) return;
        int kb = blockIdx.x - MM;
        int bx = kb / 12, by = kb - bx * 12;
        int ty = threadIdx.x >> 4, tx = threadIdx.x & 15;
        int m = bx * 16 + ty, p = by * 16 + tx;
        __shared__ float Zm[16][17], Zp[16][17];
        float d = 0.0f;
        for (int qc = 0; qc < 12; qc++) {
            int q0 = qc * 16;
            float inv_ls = 1.0f / kern_ls[q0 + tx];
            Zm[ty][tx] = Z[(bx * 16 + ty) * DIN + q0 + tx] * inv_ls;
            Zp[ty][tx] = Z[(by * 16 + ty) * DIN + q0 + tx] * inv_ls;
            __syncthreads();
            #pragma unroll
            for (int k = 0; k < 16; k++) {
                float t = Zm[ty][k] - Zp[tx][k];
                d = fmaf(t, t, d);
            }
            __syncthreads();
        }
        ws[OFF_D2ZZ + m * MM + p] = d;
        float kv = *kern_var;
        ws[OFF_KUU + m * MM + p] = kv * __expf(-0.5f * d) + ((m == p) ? JITTER : 0.0f);
    }
}

// ---------------- psi2: sum over surviving n, finalize fused ----------------
#define ZR 196   // LDS row stride
__global__ __launch_bounds__(256) void k_psi2(
    const float* __restrict__ Z, const float* __restrict__ kern_var,
    float* __restrict__ ws)
{
    int count = rd_cnt(ws, 12);
    int gflag = rd_cnt(ws, 14);
    int tx = threadIdx.x & 15, ty = threadIdx.x >> 4;
    int m0 = blockIdx.x * 32, p0 = blockIdx.y * 32;
    int mA = m0 + 2 * ty, pA = p0 + 2 * tx;
    float* P2 = ws + OFF_PSI2;
    if (count == 0) {
        if (gflag != 0) {   // chol2 will read psi2: provide exact zeros
            P2[(mA    ) * MM + pA    ] = 0.0f;
            P2[(mA    ) * MM + pA + 1] = 0.0f;
            P2[(mA + 1) * MM + pA    ] = 0.0f;
            P2[(mA + 1) * MM + pA + 1] = 0.0f;
        }
        return;
    }
    float a00 = 0, a01 = 0, a10 = 0, a11 = 0;
    {
        __shared__ __align__(16) float Zm[32 * ZR], Zp[32 * ZR];
        for (int idx = threadIdx.x; idx < 32 * DIN; idx += 256) {
            int r = idx / DIN, q = idx - r * DIN;
            Zm[r * ZR + q] = Z[(m0 + r) * DIN + q];
            Zp[r * ZR + q] = Z[(p0 + r) * DIN + q];
        }
        __syncthreads();
        const float* w2base = ws + OFF_W2;
        const float* F      = ws + OFF_F;
        const float* s2arr  = ws + OFF_S2;
        const int* list     = (const int*)(ws + OFF_NLIST);
        const float4* zm0 = (const float4*)(Zm + (2 * ty    ) * ZR);
        const float4* zm1 = (const float4*)(Zm + (2 * ty + 1) * ZR);
        const float4* zp0 = (const float4*)(Zp + (2 * tx    ) * ZR);
        const float4* zp1 = (const float4*)(Zp + (2 * tx + 1) * ZR);
        for (int li = 0; li < count; li++) {
            int n = list[li];
            const float4* w2p = (const float4*)(w2base + n * DIN);
            float e00 = 0, e01 = 0, e10 = 0, e11 = 0;
            #pragma unroll 4
            for (int g = 0; g < DIN / 4; g++) {
                float4 w  = w2p[g];
                float4 a  = zm0[g], b = zm1[g], c = zp0[g], d = zp1[g];
                float wp0, wp1;
                wp0 = w.x * c.x; wp1 = w.x * d.x;
                e00 = fmaf(a.x, wp0, e00); e01 = fmaf(a.x, wp1, e01);
                e10 = fmaf(b.x, wp0, e10); e11 = fmaf(b.x, wp1, e11);
                wp0 = w.y * c.y; wp1 = w.y * d.y;
                e00 = fmaf(a.y, wp0, e00); e01 = fmaf(a.y, wp1, e01);
                e10 = fmaf(b.y, wp0, e10); e11 = fmaf(b.y, wp1, e11);
                wp0 = w.z * c.z; wp1 = w.z * d.z;
                e00 = fmaf(a.z, wp0, e00); e01 = fmaf(a.z, wp1, e01);
                e10 = fmaf(b.z, wp0, e10); e11 = fmaf(b.z, wp1, e11);
                wp0 = w.w * c.w; wp1 = w.w * d.w;
                e00 = fmaf(a.w, wp0, e00); e01 = fmaf(a.w, wp1, e01);
                e10 = fmaf(b.w, wp0, e10); e11 = fmaf(b.w, wp1, e11);
            }
            float s2n = s2arr[n];
            float Fm0 = F[n * MM + mA], Fm1 = F[n * MM + mA + 1];
            float Fp0 = F[n * MM + pA], Fp1 = F[n * MM + pA + 1];
            a00 += __expf(s2n + Fm0 + Fp0 - 0.5f * e00);
            a01 += __expf(s2n + Fm0 + Fp1 - 0.5f * e01);
            a10 += __expf(s2n + Fm1 + Fp0 - 0.5f * e10);
            a11 += __expf(s2n + Fm1 + Fp1 - 0.5f * e11);
        }
    }
    float kv = *kern_var; float kv2 = kv * kv;
    const float* dz = ws + OFF_D2ZZ;
    P2[(mA    ) * MM + pA    ] = kv2 * __expf(-0.25f * dz[(mA    ) * MM + pA    ]) * a00;
    P2[(mA    ) * MM + pA + 1] = kv2 * __expf(-0.25f * dz[(mA    ) * MM + pA + 1]) * a01;
    P2[(mA + 1) * MM + pA    ] = kv2 * __expf(-0.25f * dz[(mA + 1) * MM + pA    ]) * a10;
    P2[(mA + 1) * MM + pA + 1] = kv2 * __expf(-0.25f * dz[(mA + 1) * MM + pA + 1]) * a11;
}

// ---------------- dual blocked LDL^T (block 0: Kuu, block 1: C2) ------------
#define ALD 196
#define NB  32
__global__ __launch_bounds__(256) void k_chol2(float* __restrict__ ws,
                                               const float* __restrict__ lik)
{
    if (rd_cnt(ws, 12) == 0 && rd_cnt(ws, 14) == 0) return;  // ldB=0, trace=0, c=0
    __shared__ __align__(16) float A[MM * ALD];
    int tid = threadIdx.x;
    bool isC2 = (blockIdx.x == 1);
    const float* Kuu  = ws + OFF_KUU;
    const float* psi2 = ws + OFF_PSI2;
    float inv_s2 = 1.0f / (*lik);
    for (int idx = tid; idx < MM * MM; idx += 256) {
        int i = idx / MM, j = idx - i * MM;
        float v = Kuu[idx];
        if (isC2) v = fmaf(psi2[idx], inv_s2, v);
        A[i * ALD + j] = v;
    }
    __syncthreads();

    float logacc = 0.0f;
    int ty = tid >> 4, tx = tid & 15;
    for (int p = 0; p < MM / NB; p++) {
        int k0 = p * NB;
        int e  = k0 + NB;
        if (tid < 64) {
            int lane = tid;
            float P[3][NB];
            #pragma unroll
            for (int s = 0; s < 3; s++) {
                int r = lane + 64 * s;
                #pragma unroll
                for (int g = 0; g < NB / 4; g++) {
                    float4 v = *(const float4*)&A[r * ALD + k0 + 4 * g];
                    P[s][4*g] = v.x; P[s][4*g+1] = v.y; P[s][4*g+2] = v.z; P[s][4*g+3] = v.w;
                }
            }
            int sD = k0 >> 6;
            int lD = k0 & 63;
            #pragma unroll
            for (int c = 0; c < NB; c++) {
                int k = k0 + c;
                float colc = (sD == 0) ? P[0][c] : ((sD == 1) ? P[1][c] : P[2][c]);
                float dkk = __shfl(colc, lD + c);
                float inv = 1.0f / dkk;
                logacc += logf(dkk);
                float m0 = (lane       > k) ? P[0][c] * inv : 0.0f;
                float m1 = (lane + 64  > k) ? P[1][c] * inv : 0.0f;
                float m2 = (lane + 128 > k) ? P[2][c] * inv : 0.0f;
                P[0][c] = (lane       > k) ? m0 : P[0][c];
                P[1][c] = (lane + 64  > k) ? m1 : P[1][c];
                P[2][c] = (lane + 128 > k) ? m2 : P[2][c];
                #pragma unroll
                for (int j = c + 1; j < NB; j++) {
                    float w = __shfl(colc, lD + j);
                    P[0][j] = fmaf(-m0, w, P[0][j]);
                    P[1][j] = fmaf(-m1, w, P[1][j]);
                    P[2][j] = fmaf(-m2, w, P[2][j]);
                }
            }
            #pragma unroll
            for (int s = 0; s < 3; s++) {
                int r = lane + 64 * s;
                #pragma unroll
                for (int g = 0; g < NB / 4; g++) {
                    float4 v = make_float4(P[s][4*g], P[s][4*g+1], P[s][4*g+2], P[s][4*g+3]);
                    *(float4*)&A[r * ALD + k0 + 4 * g] = v;
                }
            }
        }
        __syncthreads();
        int T = MM - e;
        if (T > 0) {
            for (int idx = tid; idx < NB * T; idx += 256) {
                int c = idx / T, j = e + (idx - c * T);
                float d = A[(k0 + c) * ALD + (k0 + c)];
                A[(k0 + c) * ALD + j] = A[j * ALD + k0 + c] * sqrtf(d);
            }
            __syncthreads();
            int nT = (T + 127) / 128;
            for (int bi = 0; bi < nT; bi++)
            for (int bj = 0; bj < nT; bj++) {
                int i0 = e + 128 * bi + 8 * ty;
                int j0 = e + 128 * bj + 8 * tx;
                int ic = (i0 < MM - 8) ? i0 : (MM - 8);
                int jc = (j0 < MM - 8) ? j0 : (MM - 8);
                float4 acc[8][2];
                #pragma unroll
                for (int r = 0; r < 8; r++) {
                    acc[r][0] = *(const float4*)&A[(ic + r) * ALD + jc];
                    acc[r][1] = *(const float4*)&A[(ic + r) * ALD + jc + 4];
                }
                #pragma unroll 4
                for (int c = 0; c < NB; c++) {
                    const float* row = &A[(k0 + c) * ALD];
                    float4 av0 = *(const float4*)&row[ic];
                    float4 av1 = *(const float4*)&row[ic + 4];
                    float4 bv0 = *(const float4*)&row[jc];
                    float4 bv1 = *(const float4*)&row[jc + 4];
                    float avs[8] = {av0.x, av0.y, av0.z, av0.w, av1.x, av1.y, av1.z, av1.w};
                    #pragma unroll
                    for (int r = 0; r < 8; r++) {
                        float a = avs[r];
                        acc[r][0].x = fmaf(-a, bv0.x, acc[r][0].x);
                        acc[r][0].y = fmaf(-a, bv0.y, acc[r][0].y);
                        acc[r][0].z = fmaf(-a, bv0.z, acc[r][0].z);
                        acc[r][0].w = fmaf(-a, bv0.w, acc[r][0].w);
                        acc[r][1].x = fmaf(-a, bv1.x, acc[r][1].x);
                        acc[r][1].y = fmaf(-a, bv1.y, acc[r][1].y);
                        acc[r][1].z = fmaf(-a, bv1.z, acc[r][1].z);
                        acc[r][1].w = fmaf(-a, bv1.w, acc[r][1].w);
                    }
                }
                if (ic == i0 && jc == j0) {
                    #pragma unroll
                    for (int r = 0; r < 8; r++) {
                        *(float4*)&A[(i0 + r) * ALD + j0]     = acc[r][0];
                        *(float4*)&A[(i0 + r) * ALD + j0 + 4] = acc[r][1];
                    }
                }
            }
            __syncthreads();
        }
    }
    float* dst = ws + (isC2 ? OFF_LC2 : OFF_LC);
    for (int idx = tid; idx < MM * MM; idx += 256) {
        int i = idx / MM, j = idx - i * MM;
        dst[idx] = A[i * ALD + j];
    }
    if (tid == 0) ws[OFF_SCAL + (isC2 ? 8 : 7)] = 0.5f * logacc;
}

// ---- merged: blocks 0..191 -> V col (gate cnt2); 192..203 -> solve12 ------
__global__ __launch_bounds__(64) void k_trinvsolve(float* __restrict__ ws)
{
    if (blockIdx.x < MM) {
        if (rd_cnt(ws, 12) == 0) return;
        const float* L = ws + OFF_LC;
        float* V = ws + OFF_V;
        int j = blockIdx.x, l = threadIdx.x;
        int k0 = j + l, k1 = k0 + 64, k2 = k0 + 128;
        float x0 = 0, x1 = 0, x2 = 0;
        for (int i = j; i < MM; i++) {
            const float* Lr = L + i * MM;
            float s = 0.0f;
            if (k0 < i) s = fmaf(Lr[k0], x0, s);
            if (k1 < i) s = fmaf(Lr[k1], x1, s);
            if (k2 < i) s = fmaf(Lr[k2], x2, s);
            #pragma unroll
            for (int off = 1; off < 64; off <<= 1) s += __shfl_xor(s, off);
            float xi = ((i == j) ? 1.0f : 0.0f) - s;
            if (k0 == i) x0 = xi;
            if (k1 == i) x1 = xi;
            if (k2 == i) x2 = xi;
            if (l == 0) V[i * MM + j] = xi;
        }
    } else {
        if (rd_cnt(ws, 14) == 0) return;    // G == 0 -> ||Y||^2 = 0
        const float* L = ws + OFF_LC2;
        const float* G = ws + OFF_G;
        int c = blockIdx.x - MM, l = threadIdx.x;
        int k0 = l, k1 = l + 64, k2 = l + 128;
        float x0 = 0, x1 = 0, x2 = 0, ss = 0;
        for (int i = 0; i < MM; i++) {
            const float* Lr = L + i * MM;
            float s = 0.0f;
            if (k0 < i) s = fmaf(Lr[k0], x0, s);
            if (k1 < i) s = fmaf(Lr[k1], x1, s);
            if (k2 < i) s = fmaf(Lr[k2], x2, s);
            #pragma unroll
            for (int off = 1; off < 64; off <<= 1) s += __shfl_xor(s, off);
            float xi = G[i * QD + c] - s;
            if (k0 == i) x0 = xi;
            if (k1 == i) x1 = xi;
            if (k2 == i) x2 = xi;
            if (l == 0) ss += xi * xi / Lr[i];
        }
        if (l == 0) atomicAdd(&ws[OFF_SCAL + 2], ss);
    }
}

// -------- trace_raw = sum_i (V[i,:] psi2 V[i,:]^T) / d_i --------------------
__global__ __launch_bounds__(256) void k_tracedot(float* __restrict__ ws)
{
    if (rd_cnt(ws, 12) == 0) return;    // psi2 == 0 -> trace 0
    int i = blockIdx.x, tid = threadIdx.x;
    __shared__ float vrow[MM];
    const float* V = ws + OFF_V;
    const float* P = ws + OFF_PSI2;
    for (int a = tid; a < MM; a += 256) vrow[a] = (a <= i) ? V[i * MM + a] : 0.0f;
    __syncthreads();
    float acc = 0.0f;
    for (int a = tid; a <= i; a += 256) {
        const float* Pr = P + a * MM;
        float inner = 0.0f;
        for (int b = 0; b <= i; b++) inner = fmaf(Pr[b], vrow[b], inner);
        acc = fmaf(vrow[a], inner, acc);
    }
    __shared__ float red[256];
    red[tid] = acc; __syncthreads();
    if (tid < 128) red[tid] += red[tid + 128];
    __syncthreads();
    if (tid < 64) {
        float s = red[tid] + red[tid + 64];
        s = wave_reduce(s);
        if (tid == 0) {
            float di = ws[OFF_LC + i * MM + i];   // LDL diagonal
            atomicAdd(&ws[OFF_SCAL + 0], s / di);
        }
    }
}

// ---- fused sums over X_mean/X_var + last-block final assembly --------------
#define SF_BLOCKS 72
__global__ __launch_bounds__(256) void k_sumsfinal(
    const float* __restrict__ X_mean, const float* __restrict__ X_var,
    const float* __restrict__ kern_var, const float* __restrict__ lik,
    float* __restrict__ ws, float* __restrict__ out)
{
    int idx = blockIdx.x * 256 + threadIdx.x;
    float pVo = 0, pMo = 0, pLg = 0, pMb = 0;
    if (idx < NTT * QD) {
        float xm = X_mean[idx], xv = X_var[idx];
        if (idx >= LT * QD) { pVo = xv; pMo = xm * xm; pLg = logf(xv); }
        else                { pMb = xm * xm + xv; }
    }
    pVo = bfly_sum(pVo); pMo = bfly_sum(pMo); pLg = bfly_sum(pLg); pMb = bfly_sum(pMb);
    __shared__ float part[4][4];
    if ((threadIdx.x & 63) == 0) {
        int w = threadIdx.x >> 6;
        part[w][0] = pVo; part[w][1] = pMo; part[w][2] = pLg; part[w][3] = pMb;
    }
    __syncthreads();
    __shared__ int amLast;
    if (threadIdx.x == 0) {
        #pragma unroll
        for (int t = 0; t < 4; t++)
            atomicAdd(&ws[OFF_SCAL + 3 + t],
                      part[0][t] + part[1][t] + part[2][t] + part[3][t]);
        __threadfence();
        int tkt = atomicAdd((int*)(ws + OFF_SCAL) + 15, 1);
        amLast = (tkt == SF_BLOCKS - 1);
    }
    __syncthreads();
    if (!amLast || threadIdx.x != 0) return;

    // last block: assemble the bound (atomic reads for device-scope visibility)
    float trRaw = atomicAdd(&ws[OFF_SCAL + 0], 0.0f);
    float ssY   = atomicAdd(&ws[OFF_SCAL + 2], 0.0f);
    float Svo   = atomicAdd(&ws[OFF_SCAL + 3], 0.0f);
    float Smo2  = atomicAdd(&ws[OFF_SCAL + 4], 0.0f);
    float Slog  = atomicAdd(&ws[OFF_SCAL + 5], 0.0f);
    float Smb   = atomicAdd(&ws[OFF_SCAL + 6], 0.0f);
    float ldK   = atomicAdd(&ws[OFF_SCAL + 7], 0.0f);
    float ldC2  = atomicAdd(&ws[OFF_SCAL + 8], 0.0f);
    float kv = *kern_var, s2v = *lik;
    float inv_s2 = 1.0f / s2v;
    const float lp2pi = 1.8378770664093453f;  // log(2*pi)
    float trA = trRaw * inv_s2;
    float ldB = 2.0f * (ldC2 - ldK);
    float sc2 = ssY * inv_s2 * inv_s2;
    float ND = 18000.0f;   // (Nt-Lt)*D
    float Df = 12.0f;
    float bound = -0.5f * ND * (lp2pi + logf(s2v));
    bound += -0.5f * inv_s2 * (Svo + Smo2);
    bound += -0.5f * Df * ((kv * 1500.0f) * inv_s2 - trA);
    bound += -0.5f * Df * ldB;
    bound += 0.5f * sc2;
    bound += 0.5f * Slog + 0.5f * ND * lp2pi;      // ent
    bound += -96.0f * lp2pi - 0.5f * Smb;          // ent2 (Lt*D = 96)
    out[0] = bound;
}

extern "C" void kernel_launch(void* const* d_in, const int* in_sizes, int n_in,
                              void* d_out, int out_size, void* d_ws, size_t ws_size,
                              hipStream_t stream)
{
    const float* Xm_m    = (const float*)d_in[1];
    const float* Xm_v    = (const float*)d_in[2];
    const float* Z       = (const float*)d_in[3];
    const float* X_mean  = (const float*)d_in[4];
    const float* X_var   = (const float*)d_in[5];
    const float* kern_var= (const float*)d_in[6];
    const float* kern_ls = (const float*)d_in[7];
    const float* lik_var = (const float*)d_in[8];
    float* ws  = (float*)d_ws;
    float* out = (float*)d_out;

    // zero G + scalar slots/flags/ticket (contiguous region)
    hipMemsetAsync(ws + OFF_G, 0, (MM * QD + 16) * sizeof(float), stream);

    k_prep<<<NR / 4, 256, 0, stream>>>(Xm_m, Xm_v, X_mean, X_var, kern_ls, ws);
    k_psi1bc<<<dim3(94, 12, 2), 256, 0, stream>>>(Z, kern_var, ws);     // gated
    k_gkuu<<<MM + 144, 256, 0, stream>>>(Z, kern_ls, kern_var, X_mean, ws); // gated
    k_psi2<<<dim3(6, 6), 256, 0, stream>>>(Z, kern_var, ws);            // gated
    k_chol2<<<2, 256, 0, stream>>>(ws, lik_var);                        // gated
    k_trinvsolve<<<MM + QD, 64, 0, stream>>>(ws);                       // gated
    k_tracedot<<<MM, 256, 0, stream>>>(ws);                             // gated
    k_sumsfinal<<<SF_BLOCKS, 256, 0, stream>>>(X_mean, X_var, kern_var, lik_var, ws, out);
}